// Round 5
// baseline (162.874 us; speedup 1.0000x reference)
//
#include <hip/hip_runtime.h>
#include <cstdint>

typedef __attribute__((ext_vector_type(8))) __bf16 bf16x8;
typedef __attribute__((ext_vector_type(4))) float f32x4;
typedef __attribute__((ext_vector_type(4))) uint32_t u32x4;

// ---- problem constants ----
#define NB   16
#define CIN  256
#define COUT 256
#define HP   66          // padded H
#define WP   66          // padded W
#define KTOT 2304        // 9*256
#define XPB  (HP*WP*256)            // elems per batch image = 1,115,136
#define XPAD_ELEMS (NB*XPB)

__device__ __forceinline__ uint16_t f2bf(float f) {
  uint32_t u = __builtin_bit_cast(uint32_t, f);
  u = (u + 0x7FFFu + ((u >> 16) & 1u)) >> 16;   // round-to-nearest-even
  return (uint16_t)u;
}

// ---------------- fused prep: xpose (2048 blk) | border (1040 blk) | wprep (288 blk)
__global__ void prep_kernel(const float* __restrict__ x, const float* __restrict__ w,
                            uint16_t* __restrict__ xpad, uint16_t* __restrict__ bw) {
  const int bid = blockIdx.x;
  const int tid = threadIdx.x;
  if (bid < 2048) {
    // transpose+cast: x NCHW fp32 -> xpad[b][h+1][w+1][c] bf16 (interior only)
    const int lane = tid & 63;
    const int wvi = tid >> 6;                 // 0..3
    const int chalf = bid & 1;
    const int h = (bid >> 1) & 63;
    const int b = bid >> 7;
    const int cg = lane >> 4;                 // 0..3
    const int w4 = (lane & 15) * 4;           // 0,4,...,60
    const int c0 = chalf * 128 + wvi * 32 + cg * 8;   // 8-channel group
    const float* src = x + ((size_t)(b * 256 + c0) * 64 + h) * 64 + w4;
    f32x4 v[8];
    #pragma unroll
    for (int j = 0; j < 8; ++j)
      v[j] = *(const f32x4*)(src + (size_t)j * 4096);
    uint16_t* dst = xpad + ((size_t)(b * HP + h + 1) * WP + 1 + w4) * 256 + c0;
    #pragma unroll
    for (int p = 0; p < 4; ++p) {             // 4 pixels per thread
      u32x4 d;
      #pragma unroll
      for (int k = 0; k < 4; ++k)
        d[k] = (uint32_t)f2bf(v[2 * k][p]) | ((uint32_t)f2bf(v[2 * k + 1][p]) << 16);
      *(u32x4*)(dst + p * 256) = d;
    }
  } else if (bid < 3088) {
    // zero the pad border (u64 stores)
    const int idx = (bid - 2048) * 256 + tid;   // 0 .. 266239 exact
    const int b = idx / 16640;
    const int r = idx - b * 16640;
    uint64_t* base = (uint64_t*)(xpad + (size_t)b * XPB);
    int off;
    if (r < 4224) {                    // h=0 full row
      off = r;
    } else if (r < 8448) {             // h=65 full row
      off = 274560 + (r - 4224);
    } else if (r < 12544) {            // w=0 column, h=1..64
      const int i = r - 8448;
      off = (1 + (i >> 6)) * 4224 + (i & 63);
    } else {                           // w=65 column, h=1..64
      const int i = r - 12544;
      off = (1 + (i >> 6)) * 4224 + 4160 + (i & 63);
    }
    base[off] = 0;
  } else {
    // weight reorder: w[co][ci][3][3] fp32 -> bw[co][tap][ci] bf16
    const int gid = (bid - 3088) * 256 + tid;   // 0 .. 73727
    const int co = gid / 288;                   // 288 = 9 taps * 32 ci-groups
    const int r = gid - co * 288;
    const int tap = r >> 5;
    const int ci0 = (r & 31) * 8;
    u32x4 d;
    #pragma unroll
    for (int k = 0; k < 4; ++k) {
      const float v0 = w[((co * 256 + ci0 + 2 * k + 0) * 9) + tap];
      const float v1 = w[((co * 256 + ci0 + 2 * k + 1) * 9) + tap];
      d[k] = (uint32_t)f2bf(v0) | ((uint32_t)f2bf(v1) << 16);
    }
    *(u32x4*)(bw + co * KTOT + tap * 256 + ci0) = d;
  }
}

// ---------------- async 16B global -> LDS --------------------------------------------
__device__ __forceinline__ void gl_lds16(const void* g, void* l) {
  __builtin_amdgcn_global_load_lds(
      (__attribute__((address_space(1))) void*)(uintptr_t)g,
      (__attribute__((address_space(3))) void*)(uint32_t)(uintptr_t)l,
      16, 0, 0);
}

// ---------------- implicit GEMM v6: BM=128, BN=128, BK=64; 256 threads (4 waves) ----
// Wave grid 2x2, wave tile 64x64 (acc[4][4]).
// A: LDS-staged, 2 buffers x 16 KB, depth-1 prefetch, plain __syncthreads()
//    (compiler vmcnt(0)+lgkmcnt(0) drain: stage writes landed AND prior readers done).
// B: global->VGPR direct (1.18 MB, L2-resident), double-buffered registers,
//    prefetched one iter ahead (compiler-tracked load waits -> no manual vmcnt).
// FIX vs round 4: EVERY sub-iteration prefetches exactly it+1 into the opposite
//    buffer (the odd branch previously used it+2, duplicating/skipping K-terms).
// LDS traffic: 48 KB/iter/CU (was 96 KB) -> MFMA pipe (~620 cyc/iter) is the floor.
__global__ __launch_bounds__(256, 1) void gemm_kernel(
    const uint16_t* __restrict__ xpad, const uint16_t* __restrict__ bw,
    const float* __restrict__ bias, float* __restrict__ out) {
  __shared__ uint16_t lA[2][128 * 64];   // 16 KB per buffer, 32 KB total
  const int tid = threadIdx.x;
  const int wv = tid >> 6, lane = tid & 63;
  const int quad = lane >> 4, l15 = lane & 15, l7 = lane & 7;
  const int wm = wv >> 1, wn = wv & 1;     // 2x2 wave grid, 64x64 tiles

  // XCD swizzle: both n-tiles of one m-tile + consecutive m-tiles on one XCD
  const int xcd = blockIdx.x & 7;
  const int grp = blockIdx.x >> 3;        // 0..31 per XCD
  const int mtile = (xcd << 4) + (grp >> 1);
  const int ntile = grp & 1;
  const int n0 = ntile * 128;
  const int m0 = mtile * 128;
  const int bidx = m0 >> 10;              // batch image
  const int q0 = m0 & 1023;               // permuted pixel offset (multiple of 128)

  // A staging: 4 chunk-slots/thread (1024 chunks of 16B); XOR chunk swizzle
  int a_goff[4];
  #pragma unroll
  for (int t = 0; t < 4; ++t) {
    const int slot = t * 256 + tid;
    const int row = slot >> 3;            // 0..127
    const int kc = (slot & 7) ^ (row & 7);
    const int p = q0 + row;
    const int oh = 2 * ((p >> 4) & 15) + ((p >> 9) & 1);
    const int ow = 2 * (p & 15) + ((p >> 8) & 1);
    a_goff[t] = ((bidx * HP + 2 * oh) * WP + 2 * ow) * 256 + kc * 8;
  }

  // B per-lane column pointers: frag(c,s) = 16B of bw at col*KTOT + (s*4+quad)*8
  // (byte-identical to the proven LDS-path fragment: chunk XOR cancels on read)
  const uint16_t* bcolp[4];
  #pragma unroll
  for (int c = 0; c < 4; ++c)
    bcolp[c] = bw + (size_t)(n0 + wn * 64 + c * 16 + l15) * KTOT + quad * 8;

  // A LDS frag byte-offsets (swizzle-matched)
  int aoff[4][2];
  #pragma unroll
  for (int r = 0; r < 4; ++r)
    #pragma unroll
    for (int s = 0; s < 2; ++s)
      aoff[r][s] = (wm * 64 + r * 16 + l15) * 128 + (((s * 4 + quad) ^ l7) * 16);

  f32x4 acc[4][4];
  #pragma unroll
  for (int r = 0; r < 4; ++r)
    #pragma unroll
    for (int c = 0; c < 4; ++c)
      acc[r][c] = (f32x4){0.f, 0.f, 0.f, 0.f};

  auto stageA = [&](int it, int buf) {
    const int tap = it >> 2;
    const int kh = tap / 3, kw = tap - kh * 3;
    const int ci0 = (it & 3) << 6;
    const uint16_t* aptr = xpad + (kh * WP + kw) * 256 + ci0;
    char* la_ = (char*)&lA[buf][0];
    #pragma unroll
    for (int t = 0; t < 4; ++t)
      gl_lds16(aptr + a_goff[t], la_ + (t * 256 + wv * 64) * 16);
  };

  auto loadB = [&](int it, bf16x8* dst) {   // dst[c*2+s], 8 frags = 32 VGPR
    const int tap = it >> 2;
    const int koff = tap * 256 + ((it & 3) << 6);
    #pragma unroll
    for (int c = 0; c < 4; ++c)
      #pragma unroll
      for (int s = 0; s < 2; ++s)
        dst[c * 2 + s] = *(const bf16x8*)(bcolp[c] + koff + s * 32);
  };

  auto compute = [&](int buf, const bf16x8* bcur) {
    const char* la = (const char*)&lA[buf][0];
    #pragma unroll
    for (int s = 0; s < 2; ++s) {
      bf16x8 af[4];
      #pragma unroll
      for (int r = 0; r < 4; ++r) af[r] = *(const bf16x8*)(la + aoff[r][s]);
      #pragma unroll
      for (int r = 0; r < 4; ++r)
        #pragma unroll
        for (int c = 0; c < 4; ++c)
          acc[r][c] = __builtin_amdgcn_mfma_f32_16x16x32_bf16(af[r], bcur[c * 2 + s], acc[r][c], 0, 0, 0);
    }
  };

  bf16x8 bregA[8], bregB[8];

  // prologue: A(0) -> LDS buf0, B(0) -> regs
  stageA(0, 0);
  loadB(0, bregA);

  // steady: 17 double-iterations cover it = 0..33; peel it = 34, 35
  // invariant at top of sub-iteration `it`: buf(it&1) = A(it), breg(cur) = B(it);
  // each sub-iteration prefetches it+1 into the opposite buffer/regs.
  for (int ih = 0; ih < 17; ++ih) {
    {
      const int it = 2 * ih;               // even: compute bregA, prefetch -> bregB
      __syncthreads();                     // A(it) landed; buf(it+1&1) readers done
      stageA(it + 1, 1);
      loadB(it + 1, bregB);
      compute(0, bregA);
    }
    {
      const int it = 2 * ih + 1;           // odd: compute bregB, prefetch -> bregA
      __syncthreads();
      stageA(it + 1, 0);
      loadB(it + 1, bregA);
      compute(1, bregB);
    }
  }
  // it = 34 (buf0, bregA): prefetch it=35
  __syncthreads();
  stageA(35, 1);
  loadB(35, bregB);
  compute(0, bregA);
  // it = 35 (buf1, bregB): final
  __syncthreads();
  compute(1, bregB);

  // epilogue: row(M) = wm*64 + r*16 + quad*4 + reg, col(N) = n0 + wn*64 + c*16 + l15
  float* obase = out + (size_t)bidx * (COUT * 1024);
  #pragma unroll
  for (int c = 0; c < 4; ++c) {
    const int co = n0 + wn * 64 + c * 16 + l15;
    const float bv = bias[co];
    #pragma unroll
    for (int r = 0; r < 4; ++r) {
      const int q = q0 + wm * 64 + r * 16 + quad * 4;
      f32x4 v = acc[r][c];
      v += bv;
      *(f32x4*)(obase + (size_t)co * 1024 + q) = v;
    }
  }
}

extern "C" void kernel_launch(void* const* d_in, const int* in_sizes, int n_in,
                              void* d_out, int out_size, void* d_ws, size_t ws_size,
                              hipStream_t stream) {
  const float* x    = (const float*)d_in[0];
  const float* w    = (const float*)d_in[1];
  const float* bias = (const float*)d_in[2];
  float* out = (float*)d_out;
  uint16_t* xpad = (uint16_t*)d_ws;
  uint16_t* bwq  = xpad + XPAD_ELEMS;          // 256*2304 bf16

  prep_kernel<<<dim3(3376), dim3(256), 0, stream>>>(x, w, xpad, bwq);
  gemm_kernel<<<dim3(256), dim3(256), 0, stream>>>(xpad, bwq, bias, out);
}

// Round 6
// 162.239 us; speedup vs baseline: 1.0039x; 1.0039x over previous
//
#include <hip/hip_runtime.h>
#include <cstdint>

typedef __attribute__((ext_vector_type(8))) __bf16 bf16x8;
typedef __attribute__((ext_vector_type(4))) float f32x4;
typedef __attribute__((ext_vector_type(4))) uint32_t u32x4;

// ---- problem constants ----
#define NB   16
#define CIN  256
#define COUT 256
#define HP   66          // padded H
#define WP   66          // padded W
#define KTOT 2304        // 9*256
#define XPB  (HP*WP*256)            // elems per batch image = 1,115,136
#define XPAD_ELEMS (NB*XPB)

__device__ __forceinline__ uint16_t f2bf(float f) {
  uint32_t u = __builtin_bit_cast(uint32_t, f);
  u = (u + 0x7FFFu + ((u >> 16) & 1u)) >> 16;   // round-to-nearest-even
  return (uint16_t)u;
}

// ---------------- fused prep: xpose (2048 blk) | border (1040 blk) | wprep (288 blk)
__global__ void prep_kernel(const float* __restrict__ x, const float* __restrict__ w,
                            uint16_t* __restrict__ xpad, uint16_t* __restrict__ bw) {
  const int bid = blockIdx.x;
  const int tid = threadIdx.x;
  if (bid < 2048) {
    // transpose+cast: x NCHW fp32 -> xpad[b][h+1][w+1][c] bf16 (interior only)
    const int lane = tid & 63;
    const int wvi = tid >> 6;                 // 0..3
    const int chalf = bid & 1;
    const int h = (bid >> 1) & 63;
    const int b = bid >> 7;
    const int cg = lane >> 4;                 // 0..3
    const int w4 = (lane & 15) * 4;           // 0,4,...,60
    const int c0 = chalf * 128 + wvi * 32 + cg * 8;   // 8-channel group
    const float* src = x + ((size_t)(b * 256 + c0) * 64 + h) * 64 + w4;
    f32x4 v[8];
    #pragma unroll
    for (int j = 0; j < 8; ++j)
      v[j] = *(const f32x4*)(src + (size_t)j * 4096);
    uint16_t* dst = xpad + ((size_t)(b * HP + h + 1) * WP + 1 + w4) * 256 + c0;
    #pragma unroll
    for (int p = 0; p < 4; ++p) {             // 4 pixels per thread
      u32x4 d;
      #pragma unroll
      for (int k = 0; k < 4; ++k)
        d[k] = (uint32_t)f2bf(v[2 * k][p]) | ((uint32_t)f2bf(v[2 * k + 1][p]) << 16);
      *(u32x4*)(dst + p * 256) = d;
    }
  } else if (bid < 3088) {
    // zero the pad border (u64 stores)
    const int idx = (bid - 2048) * 256 + tid;   // 0 .. 266239 exact
    const int b = idx / 16640;
    const int r = idx - b * 16640;
    uint64_t* base = (uint64_t*)(xpad + (size_t)b * XPB);
    int off;
    if (r < 4224) {                    // h=0 full row
      off = r;
    } else if (r < 8448) {             // h=65 full row
      off = 274560 + (r - 4224);
    } else if (r < 12544) {            // w=0 column, h=1..64
      const int i = r - 8448;
      off = (1 + (i >> 6)) * 4224 + (i & 63);
    } else {                           // w=65 column, h=1..64
      const int i = r - 12544;
      off = (1 + (i >> 6)) * 4224 + 4160 + (i & 63);
    }
    base[off] = 0;
  } else {
    // weight reorder: w[co][ci][3][3] fp32 -> bw[co][tap][ci] bf16
    const int gid = (bid - 3088) * 256 + tid;   // 0 .. 73727
    const int co = gid / 288;                   // 288 = 9 taps * 32 ci-groups
    const int r = gid - co * 288;
    const int tap = r >> 5;
    const int ci0 = (r & 31) * 8;
    u32x4 d;
    #pragma unroll
    for (int k = 0; k < 4; ++k) {
      const float v0 = w[((co * 256 + ci0 + 2 * k + 0) * 9) + tap];
      const float v1 = w[((co * 256 + ci0 + 2 * k + 1) * 9) + tap];
      d[k] = (uint32_t)f2bf(v0) | ((uint32_t)f2bf(v1) << 16);
    }
    *(u32x4*)(bw + co * KTOT + tap * 256 + ci0) = d;
  }
}

// ---------------- async 16B global -> LDS --------------------------------------------
__device__ __forceinline__ void gl_lds16(const void* g, void* l) {
  __builtin_amdgcn_global_load_lds(
      (__attribute__((address_space(1))) void*)(uintptr_t)g,
      (__attribute__((address_space(3))) void*)(uint32_t)(uintptr_t)l,
      16, 0, 0);
}

// ---------------- implicit GEMM v7: BM=128, BN=128, BK=64; 256 threads (4 waves) ----
// Wave grid 2x2, wave tile 64x64 (acc 4x4 f32x4, named acc00..acc33).
// A: LDS-staged, 2 buffers x 16 KB, depth-1 prefetch, plain __syncthreads().
// B: global->VGPR direct, double-buffered in NAMED registers pa0..7 / pb0..7.
//    v6's regression cause: bregA/bregB passed as lambda pointer -> scratch
//    (VGPR_Count 108 < the ~170 needed => arrays were demoted; rule #20).
//    All hot-loop state is now named scalars accessed via token-pasting macros --
//    nothing the compiler can demote.
__global__ __launch_bounds__(256, 1) void gemm_kernel(
    const uint16_t* __restrict__ xpad, const uint16_t* __restrict__ bw,
    const float* __restrict__ bias, float* __restrict__ out) {
  __shared__ uint16_t lA[2][128 * 64];   // 16 KB per buffer, 32 KB total
  const int tid = threadIdx.x;
  const int wv = tid >> 6, lane = tid & 63;
  const int quad = lane >> 4, l15 = lane & 15, l7 = lane & 7;
  const int wm = wv >> 1, wn = wv & 1;     // 2x2 wave grid, 64x64 tiles

  // XCD swizzle: both n-tiles of one m-tile + consecutive m-tiles on one XCD
  const int xcd = blockIdx.x & 7;
  const int grp = blockIdx.x >> 3;        // 0..31 per XCD
  const int mtile = (xcd << 4) + (grp >> 1);
  const int ntile = grp & 1;
  const int n0 = ntile * 128;
  const int m0 = mtile * 128;
  const int bidx = m0 >> 10;              // batch image
  const int q0 = m0 & 1023;               // permuted pixel offset (multiple of 128)

  // A staging: 4 chunk-slots/thread (1024 chunks of 16B); XOR chunk swizzle
  int a_goff[4];
  #pragma unroll
  for (int t = 0; t < 4; ++t) {
    const int slot = t * 256 + tid;
    const int row = slot >> 3;            // 0..127
    const int kc = (slot & 7) ^ (row & 7);
    const int p = q0 + row;
    const int oh = 2 * ((p >> 4) & 15) + ((p >> 9) & 1);
    const int ow = 2 * (p & 15) + ((p >> 8) & 1);
    a_goff[t] = ((bidx * HP + 2 * oh) * WP + 2 * ow) * 256 + kc * 8;
  }

  // B per-lane column pointers (named; frag(c,s) = 16B at col*KTOT + (s*4+quad)*8)
  const uint16_t* bcol0 = bw + (size_t)(n0 + wn * 64 + 0 * 16 + l15) * KTOT + quad * 8;
  const uint16_t* bcol1 = bw + (size_t)(n0 + wn * 64 + 1 * 16 + l15) * KTOT + quad * 8;
  const uint16_t* bcol2 = bw + (size_t)(n0 + wn * 64 + 2 * 16 + l15) * KTOT + quad * 8;
  const uint16_t* bcol3 = bw + (size_t)(n0 + wn * 64 + 3 * 16 + l15) * KTOT + quad * 8;

  // A LDS frag byte-offsets, named (aoff<r><s>), swizzle-matched
  #define AOFF(r, s) ((wm * 64 + (r) * 16 + l15) * 128 + ((((s) * 4 + quad) ^ l7) * 16))
  const int aoff00 = AOFF(0, 0), aoff01 = AOFF(0, 1);
  const int aoff10 = AOFF(1, 0), aoff11 = AOFF(1, 1);
  const int aoff20 = AOFF(2, 0), aoff21 = AOFF(2, 1);
  const int aoff30 = AOFF(3, 0), aoff31 = AOFF(3, 1);
  #undef AOFF

  f32x4 acc00{0,0,0,0}, acc01{0,0,0,0}, acc02{0,0,0,0}, acc03{0,0,0,0};
  f32x4 acc10{0,0,0,0}, acc11{0,0,0,0}, acc12{0,0,0,0}, acc13{0,0,0,0};
  f32x4 acc20{0,0,0,0}, acc21{0,0,0,0}, acc22{0,0,0,0}, acc23{0,0,0,0};
  f32x4 acc30{0,0,0,0}, acc31{0,0,0,0}, acc32{0,0,0,0}, acc33{0,0,0,0};

  auto stageA = [&](int it, int buf) {
    const int tap = it >> 2;
    const int kh = tap / 3, kw = tap - kh * 3;
    const int ci0 = (it & 3) << 6;
    const uint16_t* aptr = xpad + (kh * WP + kw) * 256 + ci0;
    char* la_ = (char*)&lA[buf][0];
    #pragma unroll
    for (int t = 0; t < 4; ++t)
      gl_lds16(aptr + a_goff[t], la_ + (t * 256 + wv * 64) * 16);
  };

  // B frags into named regs: R(2c+s) = bcol<c> + koff + s*32
  #define LOADB(it, R0, R1, R2, R3, R4, R5, R6, R7) do {                        \
    const int _ko = ((it) >> 2) * 256 + (((it) & 3) << 6);                      \
    R0 = *(const bf16x8*)(bcol0 + _ko);  R1 = *(const bf16x8*)(bcol0 + _ko + 32); \
    R2 = *(const bf16x8*)(bcol1 + _ko);  R3 = *(const bf16x8*)(bcol1 + _ko + 32); \
    R4 = *(const bf16x8*)(bcol2 + _ko);  R5 = *(const bf16x8*)(bcol2 + _ko + 32); \
    R6 = *(const bf16x8*)(bcol3 + _ko);  R7 = *(const bf16x8*)(bcol3 + _ko + 32); \
  } while (0)

  #define MFMA __builtin_amdgcn_mfma_f32_16x16x32_bf16
  #define COMPUTE(buf, R0, R1, R2, R3, R4, R5, R6, R7) do {                     \
    const char* _la = (const char*)&lA[buf][0];                                 \
    bf16x8 _a0 = *(const bf16x8*)(_la + aoff00);                                \
    bf16x8 _a1 = *(const bf16x8*)(_la + aoff10);                                \
    bf16x8 _a2 = *(const bf16x8*)(_la + aoff20);                                \
    bf16x8 _a3 = *(const bf16x8*)(_la + aoff30);                                \
    acc00 = MFMA(_a0, R0, acc00, 0,0,0);  acc01 = MFMA(_a0, R2, acc01, 0,0,0);  \
    acc02 = MFMA(_a0, R4, acc02, 0,0,0);  acc03 = MFMA(_a0, R6, acc03, 0,0,0);  \
    acc10 = MFMA(_a1, R0, acc10, 0,0,0);  acc11 = MFMA(_a1, R2, acc11, 0,0,0);  \
    acc12 = MFMA(_a1, R4, acc12, 0,0,0);  acc13 = MFMA(_a1, R6, acc13, 0,0,0);  \
    acc20 = MFMA(_a2, R0, acc20, 0,0,0);  acc21 = MFMA(_a2, R2, acc21, 0,0,0);  \
    acc22 = MFMA(_a2, R4, acc22, 0,0,0);  acc23 = MFMA(_a2, R6, acc23, 0,0,0);  \
    acc30 = MFMA(_a3, R0, acc30, 0,0,0);  acc31 = MFMA(_a3, R2, acc31, 0,0,0);  \
    acc32 = MFMA(_a3, R4, acc32, 0,0,0);  acc33 = MFMA(_a3, R6, acc33, 0,0,0);  \
    _a0 = *(const bf16x8*)(_la + aoff01);                                       \
    _a1 = *(const bf16x8*)(_la + aoff11);                                       \
    _a2 = *(const bf16x8*)(_la + aoff21);                                       \
    _a3 = *(const bf16x8*)(_la + aoff31);                                       \
    acc00 = MFMA(_a0, R1, acc00, 0,0,0);  acc01 = MFMA(_a0, R3, acc01, 0,0,0);  \
    acc02 = MFMA(_a0, R5, acc02, 0,0,0);  acc03 = MFMA(_a0, R7, acc03, 0,0,0);  \
    acc10 = MFMA(_a1, R1, acc10, 0,0,0);  acc11 = MFMA(_a1, R3, acc11, 0,0,0);  \
    acc12 = MFMA(_a1, R5, acc12, 0,0,0);  acc13 = MFMA(_a1, R7, acc13, 0,0,0);  \
    acc20 = MFMA(_a2, R1, acc20, 0,0,0);  acc21 = MFMA(_a2, R3, acc21, 0,0,0);  \
    acc22 = MFMA(_a2, R5, acc22, 0,0,0);  acc23 = MFMA(_a2, R7, acc23, 0,0,0);  \
    acc30 = MFMA(_a3, R1, acc30, 0,0,0);  acc31 = MFMA(_a3, R3, acc31, 0,0,0);  \
    acc32 = MFMA(_a3, R5, acc32, 0,0,0);  acc33 = MFMA(_a3, R7, acc33, 0,0,0);  \
  } while (0)

  bf16x8 pa0, pa1, pa2, pa3, pa4, pa5, pa6, pa7;   // B double-buffer, named
  bf16x8 pb0, pb1, pb2, pb3, pb4, pb5, pb6, pb7;

  // prologue: A(0) -> LDS buf0, B(0) -> pa
  stageA(0, 0);
  LOADB(0, pa0, pa1, pa2, pa3, pa4, pa5, pa6, pa7);

  // steady: 17 double-iterations cover it = 0..33; peel it = 34, 35.
  // invariant at top of sub-iteration it: buf(it&1) = A(it), current regs = B(it).
  for (int ih = 0; ih < 17; ++ih) {
    // even it = 2ih: compute pa, prefetch it+1 -> buf1/pb
    __syncthreads();                     // A(it) landed; buf1's prior readers done
    stageA(2 * ih + 1, 1);
    LOADB(2 * ih + 1, pb0, pb1, pb2, pb3, pb4, pb5, pb6, pb7);
    COMPUTE(0, pa0, pa1, pa2, pa3, pa4, pa5, pa6, pa7);
    // odd it = 2ih+1: compute pb, prefetch it+1 -> buf0/pa
    __syncthreads();
    stageA(2 * ih + 2, 0);
    LOADB(2 * ih + 2, pa0, pa1, pa2, pa3, pa4, pa5, pa6, pa7);
    COMPUTE(1, pb0, pb1, pb2, pb3, pb4, pb5, pb6, pb7);
  }
  // it = 34 (buf0, pa): prefetch it=35
  __syncthreads();
  stageA(35, 1);
  LOADB(35, pb0, pb1, pb2, pb3, pb4, pb5, pb6, pb7);
  COMPUTE(0, pa0, pa1, pa2, pa3, pa4, pa5, pa6, pa7);
  // it = 35 (buf1, pb): final
  __syncthreads();
  COMPUTE(1, pb0, pb1, pb2, pb3, pb4, pb5, pb6, pb7);

  // epilogue: row(M) = wm*64 + r*16 + quad*4 + reg, col(N) = n0 + wn*64 + c*16 + l15
  float* obase = out + (size_t)bidx * (COUT * 1024);
  #define STORE(r, c, A) do {                                                   \
    const int _co = n0 + wn * 64 + (c) * 16 + l15;                              \
    const int _q  = q0 + wm * 64 + (r) * 16 + quad * 4;                         \
    f32x4 _v = A; _v += bias[_co];                                              \
    *(f32x4*)(obase + (size_t)_co * 1024 + _q) = _v;                            \
  } while (0)
  STORE(0, 0, acc00); STORE(0, 1, acc01); STORE(0, 2, acc02); STORE(0, 3, acc03);
  STORE(1, 0, acc10); STORE(1, 1, acc11); STORE(1, 2, acc12); STORE(1, 3, acc13);
  STORE(2, 0, acc20); STORE(2, 1, acc21); STORE(2, 2, acc22); STORE(2, 3, acc23);
  STORE(3, 0, acc30); STORE(3, 1, acc31); STORE(3, 2, acc32); STORE(3, 3, acc33);
  #undef STORE
  #undef COMPUTE
  #undef LOADB
  #undef MFMA
}

extern "C" void kernel_launch(void* const* d_in, const int* in_sizes, int n_in,
                              void* d_out, int out_size, void* d_ws, size_t ws_size,
                              hipStream_t stream) {
  const float* x    = (const float*)d_in[0];
  const float* w    = (const float*)d_in[1];
  const float* bias = (const float*)d_in[2];
  float* out = (float*)d_out;
  uint16_t* xpad = (uint16_t*)d_ws;
  uint16_t* bwq  = xpad + XPAD_ELEMS;          // 256*2304 bf16

  prep_kernel<<<dim3(3376), dim3(256), 0, stream>>>(x, w, xpad, bwq);
  gemm_kernel<<<dim3(256), dim3(256), 0, stream>>>(xpad, bwq, bias, out);
}

// Round 7
// 150.778 us; speedup vs baseline: 1.0802x; 1.0760x over previous
//
#include <hip/hip_runtime.h>
#include <cstdint>

typedef __attribute__((ext_vector_type(8))) __bf16 bf16x8;
typedef __attribute__((ext_vector_type(4))) float f32x4;
typedef __attribute__((ext_vector_type(4))) uint32_t u32x4;

// ---- problem constants ----
#define NB   16
#define CIN  256
#define COUT 256
#define HP   66          // padded H
#define WP   66          // padded W
#define KTOT 2304        // 9*256
#define XPB  (HP*WP*256)            // elems per batch image = 1,115,136
#define XPAD_ELEMS (NB*XPB)

__device__ __forceinline__ uint16_t f2bf(float f) {
  uint32_t u = __builtin_bit_cast(uint32_t, f);
  u = (u + 0x7FFFu + ((u >> 16) & 1u)) >> 16;   // round-to-nearest-even
  return (uint16_t)u;
}

// ---------------- fused prep: xpose (2048 blk) | border (1040 blk) | wprep (288 blk)
__global__ void prep_kernel(const float* __restrict__ x, const float* __restrict__ w,
                            uint16_t* __restrict__ xpad, uint16_t* __restrict__ bw) {
  const int bid = blockIdx.x;
  const int tid = threadIdx.x;
  if (bid < 2048) {
    // transpose+cast: x NCHW fp32 -> xpad[b][h+1][w+1][c] bf16 (interior only)
    const int lane = tid & 63;
    const int wvi = tid >> 6;                 // 0..3
    const int chalf = bid & 1;
    const int h = (bid >> 1) & 63;
    const int b = bid >> 7;
    const int cg = lane >> 4;                 // 0..3
    const int w4 = (lane & 15) * 4;           // 0,4,...,60
    const int c0 = chalf * 128 + wvi * 32 + cg * 8;   // 8-channel group
    const float* src = x + ((size_t)(b * 256 + c0) * 64 + h) * 64 + w4;
    f32x4 v[8];
    #pragma unroll
    for (int j = 0; j < 8; ++j)
      v[j] = *(const f32x4*)(src + (size_t)j * 4096);
    uint16_t* dst = xpad + ((size_t)(b * HP + h + 1) * WP + 1 + w4) * 256 + c0;
    #pragma unroll
    for (int p = 0; p < 4; ++p) {             // 4 pixels per thread
      u32x4 d;
      #pragma unroll
      for (int k = 0; k < 4; ++k)
        d[k] = (uint32_t)f2bf(v[2 * k][p]) | ((uint32_t)f2bf(v[2 * k + 1][p]) << 16);
      *(u32x4*)(dst + p * 256) = d;
    }
  } else if (bid < 3088) {
    // zero the pad border (u64 stores)
    const int idx = (bid - 2048) * 256 + tid;   // 0 .. 266239 exact
    const int b = idx / 16640;
    const int r = idx - b * 16640;
    uint64_t* base = (uint64_t*)(xpad + (size_t)b * XPB);
    int off;
    if (r < 4224) {                    // h=0 full row
      off = r;
    } else if (r < 8448) {             // h=65 full row
      off = 274560 + (r - 4224);
    } else if (r < 12544) {            // w=0 column, h=1..64
      const int i = r - 8448;
      off = (1 + (i >> 6)) * 4224 + (i & 63);
    } else {                           // w=65 column, h=1..64
      const int i = r - 12544;
      off = (1 + (i >> 6)) * 4224 + 4160 + (i & 63);
    }
    base[off] = 0;
  } else {
    // weight reorder: w[co][ci][3][3] fp32 -> bw[co][tap][ci] bf16
    const int gid = (bid - 3088) * 256 + tid;   // 0 .. 73727
    const int co = gid / 288;                   // 288 = 9 taps * 32 ci-groups
    const int r = gid - co * 288;
    const int tap = r >> 5;
    const int ci0 = (r & 31) * 8;
    u32x4 d;
    #pragma unroll
    for (int k = 0; k < 4; ++k) {
      const float v0 = w[((co * 256 + ci0 + 2 * k + 0) * 9) + tap];
      const float v1 = w[((co * 256 + ci0 + 2 * k + 1) * 9) + tap];
      d[k] = (uint32_t)f2bf(v0) | ((uint32_t)f2bf(v1) << 16);
    }
    *(u32x4*)(bw + co * KTOT + tap * 256 + ci0) = d;
  }
}

// ---------------- async 16B global -> LDS --------------------------------------------
__device__ __forceinline__ void gl_lds16(const void* g, void* l) {
  __builtin_amdgcn_global_load_lds(
      (__attribute__((address_space(1))) void*)(uintptr_t)g,
      (__attribute__((address_space(3))) void*)(uint32_t)(uintptr_t)l,
      16, 0, 0);
}

// ---------------- implicit GEMM v8: BM=128, BN=64, BK=64; 256 threads (4 waves) -----
// 512 blocks -> 2 INDEPENDENT blocks/CU (8 waves/CU, 2/SIMD). Round-6 diagnosis:
// 1 block/CU phase-locks all waves behind one vmcnt(0)-draining barrier -> per-iter
// 4400 cyc (latency fully exposed, Occupancy 10%, MfmaUtil 10%). Two blocks per CU
// have independent barriers -> one block's drain overlaps the other's MFMA.
// Wave grid 2x2, wave tile 64x32 (acc 4x2) -> minimal A/B duplication.
// A: LDS-staged (2 buffers x 16 KB, depth-1 prefetch, plain __syncthreads).
// B: global->VGPR in named regs (pa0..3/pb0..3), double-buffered, prefetch 1 ahead.
// Per-CU-iter-pair walls: MFMA 620 cyc | LDS 96 KB ~750 | L2 48 KB ~860.
__global__ __launch_bounds__(256, 2) void gemm_kernel(
    const uint16_t* __restrict__ xpad, const uint16_t* __restrict__ bw,
    const float* __restrict__ bias, float* __restrict__ out) {
  __shared__ uint16_t lA[2][128 * 64];   // 16 KB per buffer, 32 KB total
  const int tid = threadIdx.x;
  const int wv = tid >> 6, lane = tid & 63;
  const int quad = lane >> 4, l15 = lane & 15, l7 = lane & 7;
  const int wm = wv >> 1, wn = wv & 1;     // 2x2 wave grid: 64 rows x 32 cols each

  // XCD swizzle: 4 n-tiles of one m-tile consecutive on one XCD (A L2-local)
  const int xcd = blockIdx.x & 7;
  const int grp = blockIdx.x >> 3;        // 0..63 per XCD
  const int mtile = xcd * 16 + (grp >> 2);   // 0..127
  const int ntile = grp & 3;                 // 0..3
  const int n0 = ntile * 64;
  const int m0 = mtile * 128;
  const int bidx = m0 >> 10;              // batch image
  const int q0 = m0 & 1023;               // permuted pixel offset (multiple of 128)

  // A staging: 4 chunk-slots/thread (1024 chunks of 16B); XOR chunk swizzle
  int a_goff[4];
  #pragma unroll
  for (int t = 0; t < 4; ++t) {
    const int slot = t * 256 + tid;
    const int row = slot >> 3;            // 0..127
    const int kc = (slot & 7) ^ (row & 7);
    const int p = q0 + row;
    const int oh = 2 * ((p >> 4) & 15) + ((p >> 9) & 1);
    const int ow = 2 * (p & 15) + ((p >> 8) & 1);
    a_goff[t] = ((bidx * HP + 2 * oh) * WP + 2 * ow) * 256 + kc * 8;
  }

  // B per-lane column pointers (wave's 32 cols = 2 x 16): frag 16B at col*KTOT+...
  const uint16_t* bcol0 = bw + (size_t)(n0 + wn * 32 + 0 * 16 + l15) * KTOT + quad * 8;
  const uint16_t* bcol1 = bw + (size_t)(n0 + wn * 32 + 1 * 16 + l15) * KTOT + quad * 8;

  // A LDS frag byte-offsets (swizzle-matched), rows = wm*64 + r*16 + l15
  #define AOFF(r, s) ((wm * 64 + (r) * 16 + l15) * 128 + ((((s) * 4 + quad) ^ l7) * 16))
  const int aoff00 = AOFF(0, 0), aoff01 = AOFF(0, 1);
  const int aoff10 = AOFF(1, 0), aoff11 = AOFF(1, 1);
  const int aoff20 = AOFF(2, 0), aoff21 = AOFF(2, 1);
  const int aoff30 = AOFF(3, 0), aoff31 = AOFF(3, 1);
  #undef AOFF

  f32x4 acc00{0,0,0,0}, acc01{0,0,0,0};
  f32x4 acc10{0,0,0,0}, acc11{0,0,0,0};
  f32x4 acc20{0,0,0,0}, acc21{0,0,0,0};
  f32x4 acc30{0,0,0,0}, acc31{0,0,0,0};

  auto stageA = [&](int it, int buf) {
    const int tap = it >> 2;
    const int kh = tap / 3, kw = tap - kh * 3;
    const int ci0 = (it & 3) << 6;
    const uint16_t* aptr = xpad + (kh * WP + kw) * 256 + ci0;
    char* la_ = (char*)&lA[buf][0];
    #pragma unroll
    for (int t = 0; t < 4; ++t)
      gl_lds16(aptr + a_goff[t], la_ + (t * 256 + wv * 64) * 16);
  };

  // B frags into named regs: R0=(c0,s0) R1=(c0,s1) R2=(c1,s0) R3=(c1,s1)
  #define LOADB(it, R0, R1, R2, R3) do {                                        \
    const int _ko = ((it) >> 2) * 256 + (((it) & 3) << 6);                      \
    R0 = *(const bf16x8*)(bcol0 + _ko);  R1 = *(const bf16x8*)(bcol0 + _ko + 32); \
    R2 = *(const bf16x8*)(bcol1 + _ko);  R3 = *(const bf16x8*)(bcol1 + _ko + 32); \
  } while (0)

  #define MFMA __builtin_amdgcn_mfma_f32_16x16x32_bf16
  #define COMPUTE(buf, R0, R1, R2, R3) do {                                     \
    const char* _la = (const char*)&lA[buf][0];                                 \
    bf16x8 _a0 = *(const bf16x8*)(_la + aoff00);                                \
    bf16x8 _a1 = *(const bf16x8*)(_la + aoff10);                                \
    bf16x8 _a2 = *(const bf16x8*)(_la + aoff20);                                \
    bf16x8 _a3 = *(const bf16x8*)(_la + aoff30);                                \
    acc00 = MFMA(_a0, R0, acc00, 0,0,0);  acc01 = MFMA(_a0, R2, acc01, 0,0,0);  \
    acc10 = MFMA(_a1, R0, acc10, 0,0,0);  acc11 = MFMA(_a1, R2, acc11, 0,0,0);  \
    acc20 = MFMA(_a2, R0, acc20, 0,0,0);  acc21 = MFMA(_a2, R2, acc21, 0,0,0);  \
    acc30 = MFMA(_a3, R0, acc30, 0,0,0);  acc31 = MFMA(_a3, R2, acc31, 0,0,0);  \
    _a0 = *(const bf16x8*)(_la + aoff01);                                       \
    _a1 = *(const bf16x8*)(_la + aoff11);                                       \
    _a2 = *(const bf16x8*)(_la + aoff21);                                       \
    _a3 = *(const bf16x8*)(_la + aoff31);                                       \
    acc00 = MFMA(_a0, R1, acc00, 0,0,0);  acc01 = MFMA(_a0, R3, acc01, 0,0,0);  \
    acc10 = MFMA(_a1, R1, acc10, 0,0,0);  acc11 = MFMA(_a1, R3, acc11, 0,0,0);  \
    acc20 = MFMA(_a2, R1, acc20, 0,0,0);  acc21 = MFMA(_a2, R3, acc21, 0,0,0);  \
    acc30 = MFMA(_a3, R1, acc30, 0,0,0);  acc31 = MFMA(_a3, R3, acc31, 0,0,0);  \
  } while (0)

  bf16x8 pa0, pa1, pa2, pa3;   // B double-buffer, named regs
  bf16x8 pb0, pb1, pb2, pb3;

  // prologue: A(0) -> LDS buf0, B(0) -> pa
  stageA(0, 0);
  LOADB(0, pa0, pa1, pa2, pa3);

  // invariant at top of sub-iteration it: lA[it&1] = A(it), current regs = B(it);
  // each sub-iteration prefetches it+1 into the opposite buffer/regs.
  for (int ih = 0; ih < 17; ++ih) {
    // even it = 2ih: compute pa, prefetch it+1 -> buf1/pb
    __syncthreads();                     // A(it),B(it) landed; buf1 readers done
    stageA(2 * ih + 1, 1);
    LOADB(2 * ih + 1, pb0, pb1, pb2, pb3);
    COMPUTE(0, pa0, pa1, pa2, pa3);
    // odd it = 2ih+1: compute pb, prefetch it+1 -> buf0/pa
    __syncthreads();
    stageA(2 * ih + 2, 0);
    LOADB(2 * ih + 2, pa0, pa1, pa2, pa3);
    COMPUTE(1, pb0, pb1, pb2, pb3);
  }
  // it = 34 (buf0, pa): prefetch it=35
  __syncthreads();
  stageA(35, 1);
  LOADB(35, pb0, pb1, pb2, pb3);
  COMPUTE(0, pa0, pa1, pa2, pa3);
  // it = 35 (buf1, pb): final
  __syncthreads();
  COMPUTE(1, pb0, pb1, pb2, pb3);

  // epilogue: row(M) = wm*64 + r*16 + quad*4 + reg, col(N) = n0 + wn*32 + c*16 + l15
  float* obase = out + (size_t)bidx * (COUT * 1024);
  #define STORE(r, c, A) do {                                                   \
    const int _co = n0 + wn * 32 + (c) * 16 + l15;                              \
    const int _q  = q0 + wm * 64 + (r) * 16 + quad * 4;                         \
    f32x4 _v = A; _v += bias[_co];                                              \
    *(f32x4*)(obase + (size_t)_co * 1024 + _q) = _v;                            \
  } while (0)
  STORE(0, 0, acc00); STORE(0, 1, acc01);
  STORE(1, 0, acc10); STORE(1, 1, acc11);
  STORE(2, 0, acc20); STORE(2, 1, acc21);
  STORE(3, 0, acc30); STORE(3, 1, acc31);
  #undef STORE
  #undef COMPUTE
  #undef LOADB
  #undef MFMA
}

extern "C" void kernel_launch(void* const* d_in, const int* in_sizes, int n_in,
                              void* d_out, int out_size, void* d_ws, size_t ws_size,
                              hipStream_t stream) {
  const float* x    = (const float*)d_in[0];
  const float* w    = (const float*)d_in[1];
  const float* bias = (const float*)d_in[2];
  float* out = (float*)d_out;
  uint16_t* xpad = (uint16_t*)d_ws;
  uint16_t* bwq  = xpad + XPAD_ELEMS;          // 256*2304 bf16

  prep_kernel<<<dim3(3376), dim3(256), 0, stream>>>(x, w, xpad, bwq);
  gemm_kernel<<<dim3(512), dim3(256), 0, stream>>>(xpad, bwq, bias, out);
}

// Round 8
// 129.415 us; speedup vs baseline: 1.2585x; 1.1651x over previous
//
#include <hip/hip_runtime.h>
#include <cstdint>

typedef __attribute__((ext_vector_type(8))) __bf16 bf16x8;
typedef __attribute__((ext_vector_type(4))) float f32x4;
typedef __attribute__((ext_vector_type(4))) uint32_t u32x4;

// ---- problem constants ----
#define NB   16
#define CIN  256
#define COUT 256
#define HP   66          // padded H
#define WP   66          // padded W
#define KTOT 2304        // 9*256
#define XPB  (HP*WP*256)            // elems per batch image = 1,115,136
#define XPAD_ELEMS (NB*XPB)

__device__ __forceinline__ uint16_t f2bf(float f) {
  uint32_t u = __builtin_bit_cast(uint32_t, f);
  u = (u + 0x7FFFu + ((u >> 16) & 1u)) >> 16;   // round-to-nearest-even
  return (uint16_t)u;
}

// ---------------- fused prep: xpose (2048 blk) | border (1040 blk) | wprep (288 blk)
__global__ void prep_kernel(const float* __restrict__ x, const float* __restrict__ w,
                            uint16_t* __restrict__ xpad, uint16_t* __restrict__ bw) {
  const int bid = blockIdx.x;
  const int tid = threadIdx.x;
  if (bid < 2048) {
    // transpose+cast: x NCHW fp32 -> xpad[b][h+1][w+1][c] bf16 (interior only)
    const int lane = tid & 63;
    const int wvi = tid >> 6;                 // 0..3
    const int chalf = bid & 1;
    const int h = (bid >> 1) & 63;
    const int b = bid >> 7;
    const int cg = lane >> 4;                 // 0..3
    const int w4 = (lane & 15) * 4;           // 0,4,...,60
    const int c0 = chalf * 128 + wvi * 32 + cg * 8;   // 8-channel group
    const float* src = x + ((size_t)(b * 256 + c0) * 64 + h) * 64 + w4;
    f32x4 v[8];
    #pragma unroll
    for (int j = 0; j < 8; ++j)
      v[j] = *(const f32x4*)(src + (size_t)j * 4096);
    uint16_t* dst = xpad + ((size_t)(b * HP + h + 1) * WP + 1 + w4) * 256 + c0;
    #pragma unroll
    for (int p = 0; p < 4; ++p) {             // 4 pixels per thread
      u32x4 d;
      #pragma unroll
      for (int k = 0; k < 4; ++k)
        d[k] = (uint32_t)f2bf(v[2 * k][p]) | ((uint32_t)f2bf(v[2 * k + 1][p]) << 16);
      *(u32x4*)(dst + p * 256) = d;
    }
  } else if (bid < 3088) {
    // zero the pad border (u64 stores)
    const int idx = (bid - 2048) * 256 + tid;   // 0 .. 266239 exact
    const int b = idx / 16640;
    const int r = idx - b * 16640;
    uint64_t* base = (uint64_t*)(xpad + (size_t)b * XPB);
    int off;
    if (r < 4224) {                    // h=0 full row
      off = r;
    } else if (r < 8448) {             // h=65 full row
      off = 274560 + (r - 4224);
    } else if (r < 12544) {            // w=0 column, h=1..64
      const int i = r - 8448;
      off = (1 + (i >> 6)) * 4224 + (i & 63);
    } else {                           // w=65 column, h=1..64
      const int i = r - 12544;
      off = (1 + (i >> 6)) * 4224 + 4160 + (i & 63);
    }
    base[off] = 0;
  } else {
    // weight reorder: w[co][ci][3][3] fp32 -> bw[co][tap][ci] bf16
    const int gid = (bid - 3088) * 256 + tid;   // 0 .. 73727
    const int co = gid / 288;                   // 288 = 9 taps * 32 ci-groups
    const int r = gid - co * 288;
    const int tap = r >> 5;
    const int ci0 = (r & 31) * 8;
    u32x4 d;
    #pragma unroll
    for (int k = 0; k < 4; ++k) {
      const float v0 = w[((co * 256 + ci0 + 2 * k + 0) * 9) + tap];
      const float v1 = w[((co * 256 + ci0 + 2 * k + 1) * 9) + tap];
      d[k] = (uint32_t)f2bf(v0) | ((uint32_t)f2bf(v1) << 16);
    }
    *(u32x4*)(bw + co * KTOT + tap * 256 + ci0) = d;
  }
}

// ---------------- async 16B global -> LDS --------------------------------------------
__device__ __forceinline__ void gl_lds16(const void* g, void* l) {
  __builtin_amdgcn_global_load_lds(
      (__attribute__((address_space(1))) void*)(uintptr_t)g,
      (__attribute__((address_space(3))) void*)(uint32_t)(uintptr_t)l,
      16, 0, 0);
}

// ---------------- implicit GEMM v9: BM=128, BN=64, BK=64; 256 threads (4 waves) -----
// = round-2 v3's PROVEN schedule (3-buffer LDS, depth-2 prefetch, counted vmcnt --
//   loads stay in flight across barriers; loop VMEM is 100% global_load_lds so the
//   manual count is exact) x round-7's 2 blocks/CU (BN=64 shrinks lB to 8 KB/buf:
//   3*(16+8)=72 KB -> 2 blocks/CU, 8 waves/CU, two independent pipelines per SIMD).
// v3 @1 block/CU measured ~31 us (1 wave/SIMD, serial chain); v8 @2 blocks but
// vmcnt(0)-draining barrier measured 50 us. This fuses the two.
// Per-stage VMEM ops/thread: A 4 + B 2 = 6. Depth-2 steady state: outstanding =
// stage(it)[6,oldest] + stage(it+1)[6] -> vmcnt(6) guarantees stage(it) landed.
// Walls/CU-iter-pair: MFMA 620 cyc | LDS 96 KB ~750 | L2 48 KB ~860 (12.8 us total).
__global__ __launch_bounds__(256, 2) void gemm_kernel(
    const uint16_t* __restrict__ xpad, const uint16_t* __restrict__ bw,
    const float* __restrict__ bias, float* __restrict__ out) {
  __shared__ uint16_t lA[3][128 * 64];   // 16 KB per buffer
  __shared__ uint16_t lB[3][64 * 64];    //  8 KB per buffer -> 72 KB total
  const int tid = threadIdx.x;
  const int wv = tid >> 6, lane = tid & 63;
  const int quad = lane >> 4, l15 = lane & 15, l7 = lane & 7;
  const int wm = wv >> 1, wn = wv & 1;     // 2x2 wave grid: wave tile 64(M) x 32(N)

  // XCD swizzle: 4 n-tiles of one m-tile consecutive on one XCD (A L2-local)
  const int xcd = blockIdx.x & 7;
  const int grp = blockIdx.x >> 3;        // 0..63 per XCD
  const int mtile = xcd * 16 + (grp >> 2);   // 0..127
  const int ntile = grp & 3;                 // 0..3
  const int n0 = ntile * 64;
  const int m0 = mtile * 128;
  const int bidx = m0 >> 10;              // batch image
  const int q0 = m0 & 1023;               // permuted pixel offset (multiple of 128)

  // A staging: 4 chunk-slots/thread (1024 chunks of 16B); XOR chunk swizzle
  int a_goff[4];
  #pragma unroll
  for (int t = 0; t < 4; ++t) {
    const int slot = t * 256 + tid;
    const int row = slot >> 3;            // 0..127
    const int kc = (slot & 7) ^ (row & 7);
    const int p = q0 + row;
    const int oh = 2 * ((p >> 4) & 15) + ((p >> 9) & 1);
    const int ow = 2 * (p & 15) + ((p >> 8) & 1);
    a_goff[t] = ((bidx * HP + 2 * oh) * WP + 2 * ow) * 256 + kc * 8;
  }
  // B staging: 2 chunk-slots/thread (512 chunks)
  int b_goff[2];
  #pragma unroll
  for (int t = 0; t < 2; ++t) {
    const int slot = t * 256 + tid;
    const int n = slot >> 3;              // 0..63
    const int kc = (slot & 7) ^ (n & 7);
    b_goff[t] = (n0 + n) * KTOT + kc * 8;
  }

  // LDS frag byte-offsets (swizzle-matched)
  int aoff[4][2], boff[2][2];
  #pragma unroll
  for (int r = 0; r < 4; ++r)
    #pragma unroll
    for (int s = 0; s < 2; ++s)
      aoff[r][s] = (wm * 64 + r * 16 + l15) * 128 + (((s * 4 + quad) ^ l7) * 16);
  #pragma unroll
  for (int c = 0; c < 2; ++c)
    #pragma unroll
    for (int s = 0; s < 2; ++s)
      boff[c][s] = (wn * 32 + c * 16 + l15) * 128 + (((s * 4 + quad) ^ l7) * 16);

  f32x4 acc[4][2];
  #pragma unroll
  for (int r = 0; r < 4; ++r)
    #pragma unroll
    for (int c = 0; c < 2; ++c)
      acc[r][c] = (f32x4){0.f, 0.f, 0.f, 0.f};

  auto stage = [&](int it, int buf) {
    const int tap = it >> 2;
    const int kh = tap / 3, kw = tap - kh * 3;
    const int ci0 = (it & 3) << 6;
    const uint16_t* aptr = xpad + (kh * WP + kw) * 256 + ci0;
    const uint16_t* bptr = bw + tap * 256 + ci0;
    char* la_ = (char*)&lA[buf][0];
    char* lb_ = (char*)&lB[buf][0];
    #pragma unroll
    for (int t = 0; t < 4; ++t)
      gl_lds16(aptr + a_goff[t], la_ + (t * 256 + wv * 64) * 16);
    #pragma unroll
    for (int t = 0; t < 2; ++t)
      gl_lds16(bptr + b_goff[t], lb_ + (t * 256 + wv * 64) * 16);
  };

  auto compute = [&](int buf) {
    const char* la = (const char*)&lA[buf][0];
    const char* lb = (const char*)&lB[buf][0];
    #pragma unroll
    for (int s = 0; s < 2; ++s) {
      bf16x8 af[4], bfr[2];
      #pragma unroll
      for (int r = 0; r < 4; ++r) af[r] = *(const bf16x8*)(la + aoff[r][s]);
      #pragma unroll
      for (int c = 0; c < 2; ++c) bfr[c] = *(const bf16x8*)(lb + boff[c][s]);
      #pragma unroll
      for (int r = 0; r < 4; ++r)
        #pragma unroll
        for (int c = 0; c < 2; ++c)
          acc[r][c] = __builtin_amdgcn_mfma_f32_16x16x32_bf16(af[r], bfr[c], acc[r][c], 0, 0, 0);
    }
  };

  // prologue: 2-deep prefetch (exact v3 structure, vmcnt 8->6 for 6 ops/stage)
  stage(0, 0);
  stage(1, 1);
  int buf = 0;
  for (int it = 0; it < 35; ++it) {
    // my stage(it)'s 6 chunks landed (stage(it+1)'s 6 may remain in flight)
    asm volatile("s_waitcnt vmcnt(6)" ::: "memory");
    __builtin_amdgcn_s_barrier();        // everyone's stage(it) landed
    asm volatile("" ::: "memory");       // keep ds_reads below the barrier
    if (it < 34) {
      int bnext = buf + 2; if (bnext >= 3) bnext -= 3;
      stage(it + 2, bnext);              // safe: last readers of bnext pre-barrier
    }
    compute(buf);
    buf = (buf == 2) ? 0 : buf + 1;
  }
  // peeled last iteration: nothing newer in flight -> full wait
  asm volatile("s_waitcnt vmcnt(0)" ::: "memory");
  __builtin_amdgcn_s_barrier();
  asm volatile("" ::: "memory");
  compute(buf);

  // epilogue: row(M) = wm*64 + r*16 + quad*4 + reg, col(N) = n0 + wn*32 + c*16 + l15
  float* obase = out + (size_t)bidx * (COUT * 1024);
  #pragma unroll
  for (int c = 0; c < 2; ++c) {
    const int co = n0 + wn * 32 + c * 16 + l15;
    const float bv = bias[co];
    #pragma unroll
    for (int r = 0; r < 4; ++r) {
      const int q = q0 + wm * 64 + r * 16 + quad * 4;
      f32x4 v = acc[r][c];
      v += bv;
      *(f32x4*)(obase + (size_t)co * 1024 + q) = v;
    }
  }
}

extern "C" void kernel_launch(void* const* d_in, const int* in_sizes, int n_in,
                              void* d_out, int out_size, void* d_ws, size_t ws_size,
                              hipStream_t stream) {
  const float* x    = (const float*)d_in[0];
  const float* w    = (const float*)d_in[1];
  const float* bias = (const float*)d_in[2];
  float* out = (float*)d_out;
  uint16_t* xpad = (uint16_t*)d_ws;
  uint16_t* bwq  = xpad + XPAD_ELEMS;          // 256*2304 bf16

  prep_kernel<<<dim3(3376), dim3(256), 0, stream>>>(x, w, xpad, bwq);
  gemm_kernel<<<dim3(512), dim3(256), 0, stream>>>(xpad, bwq, bias, out);
}